// Round 1
// baseline (150.435 us; speedup 1.0000x reference)
//
#include <hip/hip_runtime.h>
#include <math.h>

#define R_ROUTES 1152
#define N_CAPS 10
#define C_IN 8
#define D_DIM 16
#define B_BATCH 128
#define JD 160                      // N_CAPS * D_DIM
#define KK 9216                     // R_ROUTES * C_IN (GEMM K)
#define KSPLIT 48                   // 24 routes = 192 k per split
#define RS 24                       // routes per k-split
#define NG 5                        // jd groups of 32
#define BH 2                        // batch halves (occupancy split)
#define NBLK (KSPLIT * NG * BH)     // 480 blocks per iter dispatch

typedef __attribute__((ext_vector_type(8))) short short8;   // 8 bf16 (4 VGPRs)
typedef __attribute__((ext_vector_type(4))) float f32x4;    // MFMA accumulator

__device__ inline unsigned short f2bf(float f) {            // RNE fp32 -> bf16
    unsigned int u = __float_as_uint(f);
    unsigned int r = u + 0x7FFFu + ((u >> 16) & 1u);
    return (unsigned short)(r >> 16);
}
__device__ inline float bf2f(unsigned short h) {
    return __uint_as_float(((unsigned int)h) << 16);
}

// ---------------------------------------------------------------------------
// ws layout (byte offsets):
//   b_ij fp32 [1152][10]       @ 0         (46080 B)
//   s0/s1/s2 fp32 [128][160]   @ 46080     (3 x 81920 B)
//   cnt  u32                   @ 291840    (last-block counter, zeroed by prep)
//   xh   bf16 [128][9216]      @ 292096    A-layout [b][k]
//   xl   bf16 [128][9216]      @ 2651392
//   xT   bf16 [9216][128]      @ 5010688   A-layout for M2 ([rc][b])
// Lesson log:
//  R5/R6: in-kernel grid barriers ~20us each -> multi-dispatch.
//  R7/R9 (112.4us): atomic split-K KSPLIT=48 + fused squash/agree.
//  R10/R11: atomic throughput exonerated. R12: batch-split grid (48,5,2).
//  R13 (this): 7 -> 4 dispatches. Only grid-wide dep is s; b_ij update is
//    route-chunk-local -> each block redundantly recomputes squash + its own
//    24-route agreement + softmax (10 sibling blocks, bitwise identical).
//    Agreement contraction done IN MFMA REGISTERS (C/D layout: rc=quad*4+i,
//    jd=lane&15 -> float4 W load + 5 shfl_xor within 32-lane halves); no m2
//    LDS, no extra barriers. Final squash folded into iter3 via last-block
//    counter (__threadfence + agent-scope loads).
// ---------------------------------------------------------------------------

// prep: x -> bf16 hi/lo + transpose; zero b_ij, s0..s2, cnt
__global__ __launch_bounds__(256) void k_prep(
    const float* __restrict__ x, unsigned short* __restrict__ xh,
    unsigned short* __restrict__ xl, unsigned short* __restrict__ xT,
    float* __restrict__ b_ij, float* __restrict__ s_all,
    unsigned int* __restrict__ cnt) {
    __shared__ float tile[32][33];
    int bx = blockIdx.x;            // rc tile 0..287
    int by = blockIdx.y;            // b tile 0..3
    int t = threadIdx.x;
    int tx = t & 31, ty = t >> 5;
#pragma unroll
    for (int i = 0; i < 4; i++) {
        int row = ty + i * 8;       // b_local
        size_t idx = (size_t)(by * 32 + row) * KK + bx * 32 + tx;
        float v = x[idx];
        tile[row][tx] = v;
        unsigned short hi = f2bf(v);
        xh[idx] = hi;
        xl[idx] = f2bf(v - bf2f(hi));
    }
    __syncthreads();
#pragma unroll
    for (int i = 0; i < 4; i++) {
        int row = ty + i * 8;       // rc_local
        xT[(size_t)(bx * 32 + row) * B_BATCH + by * 32 + tx] = f2bf(tile[tx][row]);
    }
    int bid = by * 288 + bx;        // 0..1151
    if (bid < 240) s_all[bid * 256 + t] = 0.f;              // 240*256 == 3*20480
    else if (bid < 285) b_ij[(bid - 240) * 256 + t] = 0.f;  // 45*256 == 11520
    else if (bid == 285 && t == 0) *cnt = 0u;
}

// First GEMM iteration only (c = 0.1 uniform): stage c*W-hi (bf16) in LDS,
// MFMA (ah*bh + al*bh) over this block's 192-k x 32-jd x 64-b range,
// atomicAdd partials into s. Grid (48, 5, 2), block 256.
__global__ __launch_bounds__(256) void k_iter1(
    const unsigned short* __restrict__ xh, const unsigned short* __restrict__ xl,
    const float* __restrict__ W, float* __restrict__ s) {
    __shared__ unsigned short bhs[32][200];   // [jd_l][k_l], 400B rows (16B mult)
    int t = threadIdx.x;
    int ks = blockIdx.x, ng = blockIdx.y, bh = blockIdx.z;
    int r0 = ks * RS, jd0 = ng * 32, b_base = bh * 64;

    // stage 24 routes x 32 jd of 0.1*W hi: 768 pairs, 8 fp32 each
#pragma unroll
    for (int p = t; p < RS * 32; p += 256) {
        int rl = p >> 5, jdl = p & 31;
        const float* wp = W + ((size_t)(r0 + rl) * JD + jd0 + jdl) * C_IN;
        short8 vh;
#pragma unroll
        for (int i = 0; i < 8; i++) vh[i] = (short)f2bf(wp[i] * 0.1f);
        *(short8*)&bhs[jdl][rl * 8] = vh;    // k_local = rl*8+i
    }
    __syncthreads();

    int w = t >> 6, l = t & 63, row = l & 15, quad = l >> 4;
    const short8* pah = (const short8*)(xh + (size_t)(b_base + w * 16 + row) * KK + ks * 192);
    const short8* pal = (const short8*)(xl + (size_t)(b_base + w * 16 + row) * KK + ks * 192);
    f32x4 acc0 = {0,0,0,0}, acc1 = {0,0,0,0};
#pragma unroll
    for (int st = 0; st < 6; st++) {         // K = 192 = 6 steps of 32
        short8 Bh0 = *(const short8*)&bhs[row][st * 32 + quad * 8];
        short8 Bh1 = *(const short8*)&bhs[16 + row][st * 32 + quad * 8];
        short8 Ah = pah[st * 4 + quad], Al = pal[st * 4 + quad];
        acc0 = __builtin_amdgcn_mfma_f32_16x16x32_bf16(Ah, Bh0, acc0, 0, 0, 0);
        acc0 = __builtin_amdgcn_mfma_f32_16x16x32_bf16(Al, Bh0, acc0, 0, 0, 0);
        acc1 = __builtin_amdgcn_mfma_f32_16x16x32_bf16(Ah, Bh1, acc1, 0, 0, 0);
        acc1 = __builtin_amdgcn_mfma_f32_16x16x32_bf16(Al, Bh1, acc1, 0, 0, 0);
    }
#pragma unroll
    for (int i = 0; i < 4; i++) {            // C/D: col=lane&15 (jd), row=quad*4+i (b)
        int b0 = b_base + w * 16 + quad * 4 + i;
        atomicAdd(&s[(size_t)b0 * JD + jd0 + row],      acc0[i]);
        atomicAdd(&s[(size_t)b0 * JD + jd0 + 16 + row], acc1[i]);
    }
}

// Fused routing iteration: squash(s_prev) -> v (LDS, bf16), in-register
// agreement (M2 MFMA + W contract) for this block's 24 routes -> softmax -> c,
// stage c*W hi, main GEMM, atomicAdd into s_cur. All 10 sibling blocks of a
// route-chunk recompute the identical bupd (deterministic) -> no cross-block
// sync. WRITE_B: sibling (0,0) persists updated b_ij for the next iteration.
// LAST: last finishing block does the final squash -> out.
template <int WRITE_B, int LAST>
__global__ __launch_bounds__(256) void k_fused(
    const unsigned short* __restrict__ xh, const unsigned short* __restrict__ xl,
    const unsigned short* __restrict__ xT, const float* __restrict__ W,
    float* __restrict__ b_ij, const float* __restrict__ s_prev,
    float* __restrict__ s_cur, unsigned int* __restrict__ cnt,
    float* __restrict__ out) {
    __shared__ unsigned short vb[JD][136];    // [jd][b], +8 pad (272B, 16B mult)
    __shared__ unsigned short bhs[32][200];   // main-GEMM B staging
    __shared__ float bupd[RS][N_CAPS];
    __shared__ float cs[RS][N_CAPS];
    __shared__ unsigned int lastflag;

    int t = threadIdx.x;
    int ks = blockIdx.x, ng = blockIdx.y, bh = blockIdx.z;
    int r0 = ks * RS, jd0 = ng * 32, b_base = bh * 64;

    // --- Phase A: squash(s_prev) -> vb ---------------------------------
#pragma unroll
    for (int q = 0; q < 5; q++) {
        int pi = t * 5 + q;                  // (b, j) pair, 1280 total
        int b = pi / N_CAPS, j = pi % N_CAPS;
        const float* sp = s_prev + (size_t)b * JD + j * D_DIM;
        float sv[D_DIM], sqn = 0.f;
#pragma unroll
        for (int d = 0; d < D_DIM; d++) { sv[d] = sp[d]; sqn = fmaf(sv[d], sv[d], sqn); }
        float scale = sqn / ((1.f + sqn) * sqrtf(sqn));
#pragma unroll
        for (int d = 0; d < D_DIM; d++)
            vb[j * D_DIM + d][b] = f2bf(sv[d] * scale);
    }
    __syncthreads();

    int w = t >> 6, l = t & 63, row = l & 15, quad = l >> 4;
    int rhalf = l >> 5, cbase = (quad & 1) * 4;

    // --- Phase B: agreement, fully in registers ------------------------
    // M2[rc,jd] = sum_b xT[rc,b] * v[b,jd]; acc[i] holds M2 at
    // rc = mt*16 + quad*4 + i, jd = nt*16 + row. quads 0-1 -> route 2mt,
    // quads 2-3 -> route 2mt+1; c = (quad&1)*4 + i. Contract with W via
    // float4 load, reduce over (row, quad&1) = 5 shfl_xor in 32-lane halves.
    int rc0 = ks * 192;
    for (int mt = 0; mt < 12; mt++) {
        const short8* pa = (const short8*)(xT + (size_t)(rc0 + mt * 16 + row) * B_BATCH);
        short8 af0 = pa[quad], af1 = pa[4 + quad], af2 = pa[8 + quad], af3 = pa[12 + quad];
        for (int nt = (w + mt) & 3; nt < N_CAPS; nt += 4) {   // balanced 30/wave
            f32x4 acc = {0,0,0,0};
            acc = __builtin_amdgcn_mfma_f32_16x16x32_bf16(af0, *(const short8*)&vb[nt * 16 + row][quad * 8], acc, 0, 0, 0);
            acc = __builtin_amdgcn_mfma_f32_16x16x32_bf16(af1, *(const short8*)&vb[nt * 16 + row][32 + quad * 8], acc, 0, 0, 0);
            acc = __builtin_amdgcn_mfma_f32_16x16x32_bf16(af2, *(const short8*)&vb[nt * 16 + row][64 + quad * 8], acc, 0, 0, 0);
            acc = __builtin_amdgcn_mfma_f32_16x16x32_bf16(af3, *(const short8*)&vb[nt * 16 + row][96 + quad * 8], acc, 0, 0, 0);
            const float* wp = W + ((size_t)(r0 + 2 * mt + rhalf) * JD + nt * 16 + row) * C_IN + cbase;
            float4 w4 = *(const float4*)wp;
            float part = acc[0] * w4.x + acc[1] * w4.y + acc[2] * w4.z + acc[3] * w4.w;
#pragma unroll
            for (int off = 1; off < 32; off <<= 1) part += __shfl_xor(part, off, 32);
            if ((l & 31) == 0) bupd[2 * mt + rhalf][nt] = part * (1.f / (float)B_BATCH);
        }
    }
    __syncthreads();

    // --- Phase C: softmax over this block's 24 routes ------------------
    if (t < RS) {
        float braw[N_CAPS];
        float m = -1e30f;
#pragma unroll
        for (int j = 0; j < N_CAPS; j++) {
            float base = WRITE_B ? 0.f : b_ij[(r0 + t) * N_CAPS + j];
            braw[j] = base + bupd[t][j];
            m = fmaxf(m, braw[j]);
        }
        float e[N_CAPS], sum = 0.f;
#pragma unroll
        for (int j = 0; j < N_CAPS; j++) { e[j] = expf(braw[j] - m); sum += e[j]; }
        float inv = 1.f / sum;
#pragma unroll
        for (int j = 0; j < N_CAPS; j++) cs[t][j] = e[j] * inv;
        if (WRITE_B && ng == 0 && bh == 0) {
#pragma unroll
            for (int j = 0; j < N_CAPS; j++) b_ij[(r0 + t) * N_CAPS + j] = braw[j];
        }
    }
    __syncthreads();

    // --- Phase D: stage c*W hi -----------------------------------------
#pragma unroll
    for (int p = t; p < RS * 32; p += 256) {
        int rl = p >> 5, jdl = p & 31;
        const float* wp = W + ((size_t)(r0 + rl) * JD + jd0 + jdl) * C_IN;
        float c = cs[rl][(jd0 + jdl) >> 4];
        short8 vh;
#pragma unroll
        for (int i = 0; i < 8; i++) vh[i] = (short)f2bf(wp[i] * c);
        *(short8*)&bhs[jdl][rl * 8] = vh;
    }
    __syncthreads();

    // --- Phase E: main GEMM + atomic split-K ---------------------------
    const short8* pah = (const short8*)(xh + (size_t)(b_base + w * 16 + row) * KK + ks * 192);
    const short8* pal = (const short8*)(xl + (size_t)(b_base + w * 16 + row) * KK + ks * 192);
    f32x4 acc0 = {0,0,0,0}, acc1 = {0,0,0,0};
#pragma unroll
    for (int st = 0; st < 6; st++) {
        short8 Bh0 = *(const short8*)&bhs[row][st * 32 + quad * 8];
        short8 Bh1 = *(const short8*)&bhs[16 + row][st * 32 + quad * 8];
        short8 Ah = pah[st * 4 + quad], Al = pal[st * 4 + quad];
        acc0 = __builtin_amdgcn_mfma_f32_16x16x32_bf16(Ah, Bh0, acc0, 0, 0, 0);
        acc0 = __builtin_amdgcn_mfma_f32_16x16x32_bf16(Al, Bh0, acc0, 0, 0, 0);
        acc1 = __builtin_amdgcn_mfma_f32_16x16x32_bf16(Ah, Bh1, acc1, 0, 0, 0);
        acc1 = __builtin_amdgcn_mfma_f32_16x16x32_bf16(Al, Bh1, acc1, 0, 0, 0);
    }
#pragma unroll
    for (int i = 0; i < 4; i++) {
        int b0 = b_base + w * 16 + quad * 4 + i;
        atomicAdd(&s_cur[(size_t)b0 * JD + jd0 + row],      acc0[i]);
        atomicAdd(&s_cur[(size_t)b0 * JD + jd0 + 16 + row], acc1[i]);
    }

    // --- Phase F: last block does the final squash -> out --------------
    if (LAST) {
        __syncthreads();                     // drains this block's atomics (vmcnt0)
        if (t == 0) {
            __threadfence();                 // release to agent scope
            unsigned int old = atomicAdd(cnt, 1u);
            lastflag = (old == (unsigned)(NBLK - 1)) ? 1u : 0u;
        }
        __syncthreads();
        if (lastflag) {
            __threadfence();                 // acquire side
#pragma unroll
            for (int q = 0; q < 5; q++) {
                int pi = t * 5 + q;
                int b = pi / N_CAPS, j = pi % N_CAPS;
                float* sp = s_cur + (size_t)b * JD + j * D_DIM;
                float sv[D_DIM], sqn = 0.f;
#pragma unroll
                for (int d = 0; d < D_DIM; d++) {
                    sv[d] = __hip_atomic_load(sp + d, __ATOMIC_RELAXED, __HIP_MEMORY_SCOPE_AGENT);
                    sqn = fmaf(sv[d], sv[d], sqn);
                }
                float scale = sqn / ((1.f + sqn) * sqrtf(sqn));
#pragma unroll
                for (int d = 0; d < D_DIM; d++)
                    out[(size_t)b * JD + j * D_DIM + d] = sv[d] * scale;
            }
        }
    }
}

extern "C" void kernel_launch(void* const* d_in, const int* in_sizes, int n_in,
                              void* d_out, int out_size, void* d_ws, size_t ws_size,
                              hipStream_t stream) {
    const float* x = (const float*)d_in[0];   // [128,1152,8]
    const float* W = (const float*)d_in[1];   // [1,1152,10,16,8]
    float* out = (float*)d_out;               // [128,10,16,1]
    char* ws = (char*)d_ws;

    float*          b_ij = (float*)(ws + 0);
    float*          s0   = (float*)(ws + 46080);
    float*          s1   = (float*)(ws + 46080 + 81920);
    float*          s2   = (float*)(ws + 46080 + 163840);
    unsigned int*   cnt  = (unsigned int*)(ws + 291840);
    unsigned short* xh   = (unsigned short*)(ws + 292096);
    unsigned short* xl   = (unsigned short*)(ws + 2651392);
    unsigned short* xT   = (unsigned short*)(ws + 5010688);

    k_prep<<<dim3(288, 4), 256, 0, stream>>>(x, xh, xl, xT, b_ij, s0, cnt);

    k_iter1<<<dim3(KSPLIT, NG, BH), 256, 0, stream>>>(xh, xl, W, s0);

    // iteration 2: squash(s0) + agree -> b_ij (=upd1) + softmax + GEMM -> s1
    k_fused<1, 0><<<dim3(KSPLIT, NG, BH), 256, 0, stream>>>(
        xh, xl, xT, W, b_ij, s0, s1, cnt, out);

    // iteration 3: squash(s1) + agree (b_ij + upd2) + softmax + GEMM -> s2,
    // last block squashes s2 -> out
    k_fused<0, 1><<<dim3(KSPLIT, NG, BH), 256, 0, stream>>>(
        xh, xl, xT, W, b_ij, s1, s2, cnt, out);
}